// Round 11
// baseline (89.228 us; speedup 1.0000x reference)
//
#include <hip/hip_runtime.h>
#include <hip/hip_bf16.h>

#define B_    4096
#define D_    512         // elements = bytes per row (i8)
#define TB_   8192        // 2B rows
#define BM    64          // single-wave tile 64x64
#define BK    128         // 128 B per row per K-tile (proven 0-conflict geometry)
#define NK    4           // D_/BK
#define NTILE 128         // TB_/BM
#define NTRI  8256        // NTILE*(NTILE+1)/2 = 8*1032 (XCD-bijective)
#define INV_T 14.285714285714286f   // 1/0.07
#define SCL   (INV_T / 16129.0f)    // 1/(0.07*127*127)
#define SCL2  (SCL * 1.4426950408889634f)   // SCL/ln2 for exp2

typedef __attribute__((ext_vector_type(4))) int v4i;

#define GLOAD_LDS16(gp, lp)                                                        \
  __builtin_amdgcn_global_load_lds((const __attribute__((address_space(1))) void*)(gp), \
                                   (__attribute__((address_space(3))) void*)(lp),  \
                                   16, 0, 0)

// ---------------------------------------------------------------------------
// Kernel 1: concat + quantize fp32 -> int8 (E8[8192][512], q = rn(127 x)),
// zero L[8192]. 16 elems/thread.
// ---------------------------------------------------------------------------
__global__ void ntx_prep(const float* __restrict__ a, const float* __restrict__ b,
                         char* __restrict__ E8, float* __restrict__ L) {
  int t = blockIdx.x * blockDim.x + threadIdx.x;      // 0..262143
  int i = t * 16;
  const float* src = (i < B_ * D_) ? (a + i) : (b + (i - B_ * D_));
  v4i o;
#pragma unroll
  for (int g = 0; g < 4; ++g) {
    float4 v = ((const float4*)src)[g];
    int q0 = __float2int_rn(v.x * 127.0f) & 255;
    int q1 = __float2int_rn(v.y * 127.0f) & 255;
    int q2 = __float2int_rn(v.z * 127.0f) & 255;
    int q3 = __float2int_rn(v.w * 127.0f) & 255;
    o[g] = q0 | (q1 << 8) | (q2 << 16) | (q3 << 24);
  }
  ((v4i*)E8)[t] = o;
  if (t < TB_) L[t] = 0.0f;
}

// ---------------------------------------------------------------------------
// Kernel 2: SINGLE-WAVE blocks, ZERO barriers. 64x64 tile, BK=128, i8.
// ~10 independent waves/CU (LDS 16KB/block) -> m114 cross-wave overlap
// hides every latency class; no lockstep anywhere.
// Per K-tile: vmcnt(0) [own stage landed]; read ks0 frags; MFMA ks0;
// read ks1 frags; lgkmcnt(0) [buffer free]; stage kt+1 (L2 latency hides
// under MFMA ks1 + sibling waves); MFMA ks1.
// Chunk-XOR swizzle (chunk ^= row&7) on BOTH global source and ds_read.
// Triangular tiles; off-diag adds mirror col-sums; pos tiles tj==ti+64.
// ---------------------------------------------------------------------------
#define STG(kt)                                                                    \
  do { _Pragma("unroll") for (int r = 0; r < 8; ++r) {                             \
         GLOAD_LDS16(E8 + offA[r] + (kt) * BK, &As[r * 1024 + lane * 16]);         \
         GLOAD_LDS16(E8 + offB[r] + (kt) * BK, &Bs[r * 1024 + lane * 16]);         \
       } } while (0)

__global__ __launch_bounds__(64, 3)
void ntx_sim(const char* __restrict__ E8, float* __restrict__ L,
             float* __restrict__ pos) {
  __shared__ __align__(16) char As[BM * BK];   // 8 KB
  __shared__ __align__(16) char Bs[BM * BK];   // 8 KB

  // XCD-contiguous bijective swizzle (8256 = 8*1032)
  const int bid = blockIdx.x;
  const int t   = (bid & 7) * (NTRI / 8) + (bid >> 3);
  // decode triangular index t -> (ti, tj), ti<=tj; f(ti) = ti*(257-ti)/2
  int ti = (int)((257.0f - sqrtf(66049.0f - 8.0f * (float)t)) * 0.5f);
  while (ti * (257 - ti) / 2 > t) --ti;
  while ((ti + 1) * (256 - ti) / 2 <= t) ++ti;
  const int tj = ti + (t - ti * (257 - ti) / 2);
  const int rowTile = ti * BM, colTile = tj * BM;
  const bool diag = (ti == tj);
  const bool posT = (tj == ti + B_ / BM);   // holds s[r][r+B] on local diag

  const int lane = threadIdx.x & 63;
  const int llo = lane & 15, lhi = lane >> 4;

  // staging: tile = 64 rows x 8 chunks(16B) = 512 chunks; 8 rounds x 64 lanes.
  // source pre-swizzled (chunk ^= row&7), LDS linear (both-sides rule #21)
  unsigned offA[8], offB[8];
#pragma unroll
  for (int r = 0; r < 8; ++r) {
    int ch = r * 64 + lane, row = ch >> 3;
    int sc = ((ch & 7) ^ (row & 7)) << 4;           // byte offset in row
    offA[r] = (unsigned)(rowTile + row) * D_ + sc;
    offB[r] = (unsigned)(colTile + row) * D_ + sc;
  }
  // fragment byte-offsets (same involution on read); 16 B per lane per ks
  unsigned fA[2][4], fB[2][4];
#pragma unroll
  for (int ks = 0; ks < 2; ++ks)
#pragma unroll
    for (int m = 0; m < 4; ++m) {
      int chc = ks * 4 + lhi;
      int ra  = m * 16 + llo;
      fA[ks][m] = (unsigned)(ra * BK + (((unsigned)chc ^ (ra & 7)) << 4));
      int rb  = m * 16 + llo;
      fB[ks][m] = (unsigned)(rb * BK + (((unsigned)chc ^ (rb & 7)) << 4));
    }

  v4i acc[4][4] = {};

  STG(0);
#pragma unroll
  for (int kt = 0; kt < NK; ++kt) {
    asm volatile("s_waitcnt vmcnt(0)" ::: "memory");   // own stage landed
    v4i af[4], bf[4];
    // ---- ks = 0 ----
#pragma unroll
    for (int m = 0; m < 4; ++m) {
      af[m] = *(const v4i*)&As[fA[0][m]];
      bf[m] = *(const v4i*)&Bs[fB[0][m]];
    }
#pragma unroll
    for (int m = 0; m < 4; ++m)
#pragma unroll
      for (int n = 0; n < 4; ++n)
        acc[m][n] = __builtin_amdgcn_mfma_i32_16x16x64_i8(af[m], bf[n],
                                                          acc[m][n], 0, 0, 0);
    // ---- ks = 1 reads, then free the buffer and prefetch kt+1 ----
    v4i ag[4], bg[4];
#pragma unroll
    for (int m = 0; m < 4; ++m) {
      ag[m] = *(const v4i*)&As[fA[1][m]];
      bg[m] = *(const v4i*)&Bs[fB[1][m]];
    }
    asm volatile("s_waitcnt lgkmcnt(0)" ::: "memory"); // reads done -> LDS free
    if (kt + 1 < NK) STG(kt + 1);                      // hides under MFMA below
#pragma unroll
    for (int m = 0; m < 4; ++m)
#pragma unroll
      for (int n = 0; n < 4; ++n)
        acc[m][n] = __builtin_amdgcn_mfma_i32_16x16x64_i8(ag[m], bg[n],
                                                          acc[m][n], 0, 0, 0);
  }

  // --- epilogue (verified layout: col = lane&15, row = (lane>>4)*4 + reg) ---
  float cs[4] = {0.f, 0.f, 0.f, 0.f};
#pragma unroll
  for (int m = 0; m < 4; ++m) {
    float rs[4] = {0.f, 0.f, 0.f, 0.f};
#pragma unroll
    for (int n = 0; n < 4; ++n) {
      int gc = colTile + n * 16 + llo;
#pragma unroll
      for (int jj = 0; jj < 4; ++jj) {
        int gr = rowTile + m * 16 + lhi * 4 + jj;
        if (posT && gc - gr == B_) pos[gr] = (float)acc[m][n][jj] * SCL;
        float e = exp2f((float)acc[m][n][jj] * SCL2);
        e = (diag && gr == gc) ? 0.0f : e;
        rs[jj] += e;
        cs[n]  += e;
      }
    }
#pragma unroll
    for (int jj = 0; jj < 4; ++jj) {
      float v = rs[jj];
      v += __shfl_xor(v, 1);
      v += __shfl_xor(v, 2);
      v += __shfl_xor(v, 4);
      v += __shfl_xor(v, 8);
      if (llo == 0) {
        int gr = rowTile + m * 16 + lhi * 4 + jj;
        atomicAdd(&L[gr], v);
      }
    }
  }
  if (!diag) {
    // column sums = row sums of mirrored tile (j,i)
#pragma unroll
    for (int n = 0; n < 4; ++n) {
      float v = cs[n];
      v += __shfl_xor(v, 16);
      v += __shfl_xor(v, 32);
      if (lhi == 0) {
        int gc = colTile + n * 16 + llo;
        atomicAdd(&L[gc], v);
      }
    }
  }
}

// ---------------------------------------------------------------------------
// Kernel 3: single block: nll_r = log(L[r]) - pos[r mod B]; mean -> out.
// ---------------------------------------------------------------------------
__global__ void ntx_fin(const float* __restrict__ L, const float* __restrict__ pos,
                        float* __restrict__ out) {
  int tid = threadIdx.x;
  float s = 0.f;
#pragma unroll
  for (int k = 0; k < TB_ / 256; ++k) {
    int r = k * 256 + tid;
    s += __logf(L[r]) - pos[r & (B_ - 1)];
  }
#pragma unroll
  for (int off = 1; off < 64; off <<= 1) s += __shfl_xor(s, off);
  __shared__ float sm[4];
  if ((tid & 63) == 0) sm[tid >> 6] = s;
  __syncthreads();
  if (tid == 0) out[0] = (sm[0] + sm[1] + sm[2] + sm[3]) * (1.0f / TB_);
}

// ---------------------------------------------------------------------------
extern "C" void kernel_launch(void* const* d_in, const int* in_sizes, int n_in,
                              void* d_out, int out_size, void* d_ws, size_t ws_size,
                              hipStream_t stream) {
  const float* e1 = (const float*)d_in[0];
  const float* e2 = (const float*)d_in[1];
  float* out = (float*)d_out;
  char* E8   = (char*)d_ws;                                        // 4 MB i8
  float* L   = (float*)((char*)d_ws + (size_t)TB_ * D_);           // 32 KB
  float* pos = L + TB_;                                            // 16 KB

  ntx_prep<<<1024, 256, 0, stream>>>(e1, e2, E8, L);
  ntx_sim<<<NTRI, 64, 0, stream>>>(E8, L, pos);
  ntx_fin<<<1, 256, 0, stream>>>(L, pos, out);
}

// Round 13
// 50.268 us; speedup vs baseline: 1.7750x; 1.7750x over previous
//
#include <hip/hip_runtime.h>
#include <hip/hip_bf16.h>

#define B_    4096
#define D_    512         // elements = bytes per row (i8)
#define TB_   8192        // 2B rows
#define BM    128
#define BK    128         // 128 B per row per K-tile (R2 geometry, 0-conflict)
#define NK    4           // D_/BK
#define NTILE 64          // TB_/BM
#define NTRI  2080        // NTILE*(NTILE+1)/2 = 8*260 (XCD-bijective)
#define INV_T 14.285714285714286f   // 1/0.07
#define SCL   (INV_T / 16129.0f)    // 1/(0.07*127*127)

typedef __attribute__((ext_vector_type(4))) int v4i;

#define GLOAD_LDS16(gp, lp)                                                        \
  __builtin_amdgcn_global_load_lds((const __attribute__((address_space(1))) void*)(gp), \
                                   (__attribute__((address_space(3))) void*)(lp),  \
                                   16, 0, 0)

// ---------------------------------------------------------------------------
// Kernel 1: concat + quantize fp32 -> int8 (E8[8192][512], q = rn(127 x)).
// ---------------------------------------------------------------------------
__global__ void ntx_prep(const float* __restrict__ a, const float* __restrict__ b,
                         char* __restrict__ E8) {
  int t = blockIdx.x * blockDim.x + threadIdx.x;      // 0..262143
  int i = t * 16;
  const float* src = (i < B_ * D_) ? (a + i) : (b + (i - B_ * D_));
  v4i o;
#pragma unroll
  for (int g = 0; g < 4; ++g) {
    float4 v = ((const float4*)src)[g];
    int q0 = __float2int_rn(v.x * 127.0f) & 255;
    int q1 = __float2int_rn(v.y * 127.0f) & 255;
    int q2 = __float2int_rn(v.z * 127.0f) & 255;
    int q3 = __float2int_rn(v.w * 127.0f) & 255;
    o[g] = q0 | (q1 << 8) | (q2 << 16) | (q3 << 24);
  }
  ((v4i*)E8)[t] = o;
}

// ---------------------------------------------------------------------------
// Kernel 2: R9's i8 GEMM with an ATOMIC-FREE epilogue, writer-disambiguated
// (R12's bug: wc=0/1 waves overwrote the same Prow slot -> L halved -> ln2
// error). Fix: P2[ti][128][BM] with slot = tj*2+wc for row-partials and
// (mirror) P2[tj][ti*2+wr] for col-partials. Every slot: exactly one
// writer; all 128 slots covered (j>i rows, j<i mirror cols, j==i diag).
// ---------------------------------------------------------------------------
__global__ __launch_bounds__(256, 2)
void ntx_sim(const char* __restrict__ E8, float* __restrict__ P,
             float* __restrict__ pos) {
  __shared__ __align__(16) char As[BM * BK];   // 16 KB
  __shared__ __align__(16) char Bs[BM * BK];   // 16 KB

  // XCD-contiguous bijective swizzle (2080 = 8*260)
  const int bid = blockIdx.x;
  const int t   = (bid & 7) * (NTRI / 8) + (bid >> 3);
  // decode triangular index t -> (ti, tj), ti<=tj
  int ti = (int)((129.0f - sqrtf(16641.0f - 8.0f * (float)t)) * 0.5f);
  while (ti * (129 - ti) / 2 > t) --ti;
  while ((ti + 1) * (128 - ti) / 2 <= t) ++ti;
  const int tj = ti + (t - ti * (129 - ti) / 2);
  const int rowTile = ti * BM, colTile = tj * BM;
  const bool diag = (ti == tj);
  const bool posT = (tj == ti + B_ / BM);   // holds s[r][r+B] on local diag

  const int tid = threadIdx.x, lane = tid & 63, wave = tid >> 6;
  const int wr = wave >> 1, wc = wave & 1;
  const int llo = lane & 15, lhi = lane >> 4;

  // staging: tile = 128 rows x 8 chunks(16B) = 1024 chunks; 4 rounds x 256 thr.
  // source pre-swizzled (chunk ^= row&7), LDS linear (both-sides rule #21)
  unsigned offA[4], offB[4], ldsOf[4];
#pragma unroll
  for (int r = 0; r < 4; ++r) {
    int ch = r * 256 + tid, row = ch >> 3;
    int sc = ((ch & 7) ^ (row & 7)) << 4;           // byte offset in row
    offA[r]  = (unsigned)(rowTile + row) * D_ + sc;
    offB[r]  = (unsigned)(colTile + row) * D_ + sc;
    ldsOf[r] = (unsigned)ch * 16;
  }
  // fragment byte-offsets (same involution on read); 16 B per lane per ks
  unsigned fA[2][4], fB[2][4];
#pragma unroll
  for (int ks = 0; ks < 2; ++ks)
#pragma unroll
    for (int m = 0; m < 4; ++m) {
      int chc = ks * 4 + lhi;
      int ra  = wr * 64 + m * 16 + llo;
      fA[ks][m] = (unsigned)(ra * BK + (((unsigned)chc ^ (ra & 7)) << 4));
      int rb  = wc * 64 + m * 16 + llo;
      fB[ks][m] = (unsigned)(rb * BK + (((unsigned)chc ^ (rb & 7)) << 4));
    }

  v4i acc[4][4] = {};

  for (int kt = 0; kt < NK; ++kt) {
    const unsigned kb = (unsigned)kt * BK;
#pragma unroll
    for (int r = 0; r < 4; ++r) GLOAD_LDS16(E8 + offA[r] + kb, &As[ldsOf[r]]);
#pragma unroll
    for (int r = 0; r < 4; ++r) GLOAD_LDS16(E8 + offB[r] + kb, &Bs[ldsOf[r]]);
    __syncthreads();   // drains vmcnt: tile resident
#pragma unroll
    for (int ks = 0; ks < 2; ++ks) {
      v4i af[4], bf[4];
#pragma unroll
      for (int m = 0; m < 4; ++m) {
        af[m] = *(const v4i*)&As[fA[ks][m]];
        bf[m] = *(const v4i*)&Bs[fB[ks][m]];
      }
#pragma unroll
      for (int m = 0; m < 4; ++m)
#pragma unroll
        for (int n = 0; n < 4; ++n)
          acc[m][n] = __builtin_amdgcn_mfma_i32_16x16x64_i8(af[m], bf[n],
                                                            acc[m][n], 0, 0, 0);
    }
    __syncthreads();   // protect LDS before next staging
  }

  // --- epilogue: exp, row/col partial sums, PLAIN stores (one writer/slot) ---
  // C/D layout: col = lane&15, row = (lane>>4)*4 + reg
  float* __restrict__ Prow = P + ((size_t)ti * 2 * NTILE + (size_t)tj * 2 + wc) * BM;
  float* __restrict__ Pcol = P + ((size_t)tj * 2 * NTILE + (size_t)ti * 2 + wr) * BM;
  float cs[4] = {0.f, 0.f, 0.f, 0.f};
#pragma unroll
  for (int m = 0; m < 4; ++m) {
    float rs[4] = {0.f, 0.f, 0.f, 0.f};
#pragma unroll
    for (int n = 0; n < 4; ++n) {
      int gc = colTile + wc * 64 + n * 16 + llo;
#pragma unroll
      for (int jj = 0; jj < 4; ++jj) {
        int gr = rowTile + wr * 64 + m * 16 + lhi * 4 + jj;
        float s = (float)acc[m][n][jj] * SCL;
        if (posT && gc - gr == B_) pos[gr] = s;   // unique writer
        float e = __expf(s);
        e = (diag && gr == gc) ? 0.0f : e;
        rs[jj] += e;
        cs[n]  += e;
      }
    }
#pragma unroll
    for (int jj = 0; jj < 4; ++jj) {
      float v = rs[jj];
      v += __shfl_xor(v, 1);
      v += __shfl_xor(v, 2);
      v += __shfl_xor(v, 4);
      v += __shfl_xor(v, 8);
      if (llo == 0) Prow[wr * 64 + m * 16 + lhi * 4 + jj] = v;  // slot tj*2+wc
    }
  }
  if (diag) {
    // diag tile: the unwritten mirror slot ti*2+? — row slots tj*2+wc cover
    // j==i; col slots for j==i are the SAME slots (ti*2+wr with wr=wc role),
    // but only row-partials were stored. The other-half slots (ti*2+{0,1})
    // are exactly the two row slots -> nothing more to write.
    ;
  } else {
    // column sums = row sums of mirrored tile (j,i)
#pragma unroll
    for (int n = 0; n < 4; ++n) {
      float v = cs[n];
      v += __shfl_xor(v, 16);
      v += __shfl_xor(v, 32);
      if (lhi == 0) Pcol[wc * 64 + n * 16 + llo] = v;           // slot ti*2+wr
    }
  }
}

// ---------------------------------------------------------------------------
// Kernel 3: gather L[r] = sum over 128 slots of P2[ti][j2][rloc];
// nll = log(L) - pos; per-block partial -> par[32].
// ---------------------------------------------------------------------------
__global__ void ntx_fin1(const float* __restrict__ P, const float* __restrict__ pos,
                         float* __restrict__ par) {
  int r = blockIdx.x * 256 + threadIdx.x;     // 32 blocks x 256 rows
  int ti = r >> 7, rloc = r & 127;
  const float* base = P + (size_t)ti * 2 * NTILE * BM + rloc;
  float s = 0.f;
#pragma unroll 16
  for (int j = 0; j < 2 * NTILE; ++j) s += base[j * BM];
  float nll = __logf(s) - pos[r & (B_ - 1)];
  float v = nll;
#pragma unroll
  for (int off = 1; off < 64; off <<= 1) v += __shfl_xor(v, off);
  __shared__ float sm[4];
  if ((threadIdx.x & 63) == 0) sm[threadIdx.x >> 6] = v;
  __syncthreads();
  if (threadIdx.x == 0) par[blockIdx.x] = sm[0] + sm[1] + sm[2] + sm[3];
}

// Kernel 4: fold 32 partials -> mean
__global__ void ntx_fin2(const float* __restrict__ par, float* __restrict__ out) {
  int t = threadIdx.x;                         // 64 threads
  float s = (t < 32) ? par[t] : 0.f;
#pragma unroll
  for (int off = 1; off < 32; off <<= 1) s += __shfl_xor(s, off);
  if (t == 0) out[0] = s * (1.0f / TB_);
}

// ---------------------------------------------------------------------------
extern "C" void kernel_launch(void* const* d_in, const int* in_sizes, int n_in,
                              void* d_out, int out_size, void* d_ws, size_t ws_size,
                              hipStream_t stream) {
  const float* e1 = (const float*)d_in[0];
  const float* e2 = (const float*)d_in[1];
  float* out = (float*)d_out;
  char*  E8  = (char*)d_ws;                                       // 4 MB i8
  float* P   = (float*)((char*)d_ws + (size_t)TB_ * D_);          // 4 MB partials
  float* pos = P + (size_t)NTILE * 2 * NTILE * BM;                // 16 KB
  float* par = pos + B_;                                          // 128 B

  ntx_prep<<<1024, 256, 0, stream>>>(e1, e2, E8);
  ntx_sim<<<NTRI, 256, 0, stream>>>(E8, P, pos);
  ntx_fin1<<<TB_ / 256, 256, 0, stream>>>(P, pos, par);
  ntx_fin2<<<1, 64, 0, stream>>>(par, out);
}